// Round 9
// baseline (113374.951 us; speedup 1.0000x reference)
//
#include <hip/hip_runtime.h>
#include <math.h>
#include <cfloat>

#define NROW 4096
#define DFEAT 128
constexpr float EPS32   = 0.01f;
constexpr float GAMMA32 = (float)(5.0/5.01);   // f32(rho/(rho+eps))
constexpr float MU_S    = 1.0f/4096.0f;
constexpr float MU_F    = 1.0f/128.0f;
constexpr float TINY    = 1e-16f;

// scal: 0=pif_sum 1=cmin 2=safe 3=flag 4=ratio_s 5=pis_total

// rounding barrier: blocks -ffp-contract=fast from fusing mul into a later add
__device__ __forceinline__ float sepf(float x){ asm volatile("" : "+v"(x)); return x; }

// ---------- numpy/OpenBLAS-exact helpers ----------

// numpy pairwise leaf: 128 contiguous values, 8 accumulators, plain adds
__device__ __forceinline__ float np_leaf128(const float* a){
    float r0=a[0],r1=a[1],r2=a[2],r3=a[3],r4=a[4],r5=a[5],r6=a[6],r7=a[7];
    #pragma unroll
    for (int i=8;i<128;i+=8){
        r0+=a[i+0]; r1+=a[i+1]; r2+=a[i+2]; r3+=a[i+3];
        r4+=a[i+4]; r5+=a[i+5]; r6+=a[i+6]; r7+=a[i+7];
    }
    return ((r0+r1)+(r2+r3)) + ((r4+r5)+(r6+r7));
}

// OpenBLAS sgemv_t dot, length 128: ONE 8-lane ymm acc, stride-8
__device__ __forceinline__ float blas_dot128(const float* x, const float* y){
    float acc[8];
    #pragma unroll
    for (int p=0;p<8;p++) acc[p]=0.f;
    #pragma unroll
    for (int m=0;m<16;m++)
        #pragma unroll
        for (int p=0;p<8;p++) acc[p] = fmaf(x[m*8+p], y[m*8+p], acc[p]);
    float s0=acc[0]+acc[4], s1=acc[1]+acc[5], s2=acc[2]+acc[6], s3=acc[3]+acc[7];
    return (s0+s1)+(s2+s3);
}

// ---------- kernels ----------

__global__ void k_fill(float* __restrict__ p, int n, float v){
    int i = blockIdx.x*blockDim.x + threadIdx.x;
    if (i < n) p[i] = v;
}

__global__ __launch_bounds__(128) void k_pifsums(const float* __restrict__ pif,
        float* __restrict__ rvec, float* __restrict__ cvec, float* __restrict__ scal){
    int t = threadIdx.x;
    float rs = np_leaf128(pif + t*DFEAT);
    rvec[t] = rs;
    float cs = pif[t];
    for (int i=1;i<DFEAT;i++) cs += pif[i*DFEAT + t];
    cvec[t] = cs;
    __shared__ float ld[128];
    ld[t] = rs; __syncthreads();
    for (int h=64; h>=1; h>>=1){
        if (t<h) ld[t] = ld[2*t] + ld[2*t+1];
        __syncthreads();
    }
    if (t==0) scal[0] = ld[0];
}

// t1[i] = (X*X)[i,:] @ r — sgemv_t: 8 lanes stride-8 + blas hsum
__global__ __launch_bounds__(256) void k_tvec(const float* __restrict__ M,
        const float* __restrict__ r, float* __restrict__ out){
    int row = blockIdx.x*32 + (threadIdx.x >> 3);
    int p   = threadIdx.x & 7;
    const float* mr = M + (size_t)row*DFEAT;
    float acc = 0.f;
    #pragma unroll
    for (int m=0;m<16;m++){
        float x = mr[p + 8*m];
        float xx = x*x;
        acc = fmaf(xx, r[p + 8*m], acc);
    }
    acc += __shfl_xor(acc, 4);
    acc += __shfl_xor(acc, 1);
    acc += __shfl_xor(acc, 2);
    if (p==0) out[row] = acc;
}

// W = X @ pi_f : per-output sequential k-chain
__global__ __launch_bounds__(256) void k_gemm_w(const float* __restrict__ X,
        const float* __restrict__ pif, float* __restrict__ W){
    int o = blockIdx.x*256 + threadIdx.x;
    int i = o >> 7, j = o & 127;
    const float* xr = X + (size_t)i*DFEAT;
    float acc = 0.f;
    #pragma unroll 8
    for (int k=0;k<DFEAT;k++) acc = fmaf(xr[k], pif[k*DFEAT + j], acc);
    W[o] = acc;
}

// C = (t1+t2) + (-2 * W@Y^T); per-output sequential k-chain; block min/max
__global__ __launch_bounds__(256) void k_gemm_c(const float* __restrict__ W, const float* __restrict__ Y,
        const float* __restrict__ t1, const float* __restrict__ t2,
        float* __restrict__ C, float* __restrict__ bmin, float* __restrict__ bmax){
    __shared__ float Ws[16][132];
    __shared__ float Ys[16][132];
    int t = threadIdx.x;
    int bi = blockIdx.y, bj = blockIdx.x;
    for (int l=t; l<2048; l+=256){
        int r = l>>7, k = l&127;
        Ws[r][k] = W[(size_t)(bi*16+r)*DFEAT + k];
        Ys[r][k] = Y[(size_t)(bj*16+r)*DFEAT + k];
    }
    __syncthreads();
    int a = t >> 4, b = t & 15;
    float acc = 0.f;
    #pragma unroll 8
    for (int k=0;k<DFEAT;k++) acc = fmaf(Ws[a][k], Ys[b][k], acc);
    int gi = bi*16 + a, gj = bj*16 + b;
    float t12 = t1[gi] + t2[gj];
    float v   = t12 + (-2.0f*acc);   // *2 exact -> contraction-safe
    C[(size_t)gi*NROW + gj] = v;
    __shared__ float rmn[256], rmx[256];
    rmn[t]=v; rmx[t]=v; __syncthreads();
    for (int s=128;s;s>>=1){
        if (t<s){ rmn[t]=fminf(rmn[t],rmn[t+s]); rmx[t]=fmaxf(rmx[t],rmx[t+s]); }
        __syncthreads();
    }
    if (t==0){ int bid = bi*gridDim.x + bj; bmin[bid]=rmn[0]; bmax[bid]=rmx[0]; }
}

__global__ void k_minmax(const float* __restrict__ bmin, const float* __restrict__ bmax,
                         int n, float* __restrict__ scal){
    int t = threadIdx.x; // 256
    float mn=FLT_MAX, mx=-FLT_MAX;
    for (int i=t;i<n;i+=256){ mn=fminf(mn,bmin[i]); mx=fmaxf(mx,bmax[i]); }
    __shared__ float rmn[256], rmx[256];
    rmn[t]=mn; rmx[t]=mx; __syncthreads();
    for (int s=128;s;s>>=1){
        if (t<s){ rmn[t]=fminf(rmn[t],rmn[t+s]); rmx[t]=fmaxf(rmx[t],rmx[t+s]); }
        __syncthreads();
    }
    if (t==0){
        float cmin=rmn[0], scale=rmx[0]-rmn[0];
        scal[1]=cmin;
        scal[2]=(scale>1e-8f)? scale : 1.0f;
        scal[3]=(scale>1e-8f)? 1.0f  : 0.0f;
    }
}

// K = exp((-((C-cmin)/safe))/0.01f) — fallback (no transpose)
__global__ void k_exp(float* __restrict__ K, const float* __restrict__ scal){
    float cmin=scal[1], safe=scal[2], flag=scal[3];
    int stride = gridDim.x*blockDim.x;
    for (int i = blockIdx.x*blockDim.x+threadIdx.x; i < NROW*NROW; i += stride){
        if (flag > 0.5f){
            float sub = K[i] - cmin;
            float cn  = sub / safe;
            float arg = (-cn) / EPS32;
            K[i] = (float)exp((double)arg);
        } else {
            K[i] = 1.0f;
        }
    }
}

// fast path: K = exp(...) in place AND K^T written to KT (LDS-tiled transpose)
__global__ __launch_bounds__(256) void k_exp_t(float* __restrict__ K, float* __restrict__ KT,
        const float* __restrict__ scal){
    __shared__ float tile[64][65];
    float cmin=scal[1], safe=scal[2], flag=scal[3];
    int bi = blockIdx.y, bj = blockIdx.x;
    int t = threadIdx.x;
    for (int l=t; l<4096; l+=256){
        int r = l>>6, c = l&63;
        size_t idx = (size_t)(bi*64+r)*NROW + bj*64+c;
        float v = K[idx];
        if (flag > 0.5f){
            float sub = v - cmin;
            float cn  = sub / safe;
            float arg = (-cn) / EPS32;
            v = (float)exp((double)arg);
        } else v = 1.0f;
        K[idx] = v;
        tile[c][r] = v;
    }
    __syncthreads();
    for (int l=t; l<4096; l+=256){
        int r = l>>6, c = l&63;
        KT[(size_t)(bj*64+r)*NROW + bi*64+c] = tile[r][c];
    }
}

// a = (mu/(K@b+1e-16))^gamma ; sgemv_t: 8-lane stride-8, blas hsum; 8 rows/block,
// bv staged in LDS, deep unroll for BW saturation (2 waves/CU)
__global__ __launch_bounds__(64) void k_kb_np(const float* __restrict__ K,
        const float* __restrict__ bv, float* __restrict__ av){
    __shared__ float bvs[NROW];
    int t = threadIdx.x;
    {
        float4* d = reinterpret_cast<float4*>(bvs);
        const float4* s4 = reinterpret_cast<const float4*>(bv);
        for (int i=t;i<1024;i+=64) d[i] = s4[i];
    }
    __syncthreads();
    int row = blockIdx.x*8 + (t>>3);
    int p   = t & 7;
    const float* Kr = K + (size_t)row*NROW;
    float acc = 0.f;
    #pragma unroll 32
    for (int m=0;m<512;m++) acc = fmaf(Kr[p+8*m], bvs[p+8*m], acc);
    acc += __shfl_xor(acc, 4);
    acc += __shfl_xor(acc, 1);
    acc += __shfl_xor(acc, 2);
    if (p==0){
        float den = acc + TINY;
        float q   = MU_S / den;
        av[row] = (float)pow((double)q, (double)GAMMA32);
    }
}

// fallback kta (column walk over K)
__global__ __launch_bounds__(256) void k_kta_np(const float* __restrict__ K,
        const float* __restrict__ av, float* __restrict__ kta, float* __restrict__ bv){
    int j = blockIdx.x*256 + threadIdx.x;
    float s = 0.f;
    #pragma unroll 4
    for (int i=0;i<NROW;i++) s = fmaf(av[i], K[(size_t)i*NROW + j], s);
    kta[j] = s;
    bv[j]  = MU_S/(s + TINY);
}

// fast kta: contiguous K^T row per thread, SAME serial FMA order;
// 4-stage x 16-float4 register pipeline (reload issued 3 bodies ahead);
// av staged in LDS, consumed as float4 broadcast
__global__ __launch_bounds__(64,1) void k_kta_fast(const float* __restrict__ KT,
        const float* __restrict__ av, float* __restrict__ kta, float* __restrict__ bv){
    __shared__ float avs[NROW];
    int t = threadIdx.x;
    float4* avs4 = reinterpret_cast<float4*>(avs);
    {
        const float4* s4 = reinterpret_cast<const float4*>(av);
        for (int i=t;i<1024;i+=64) avs4[i] = s4[i];
    }
    __syncthreads();
    int j = blockIdx.x*64 + t;
    const float4* row = reinterpret_cast<const float4*>(KT + (size_t)j*NROW);
    float4 A[16], B[16], C[16], D[16];
    #pragma unroll
    for (int k=0;k<16;k++) A[k]=row[k];
    #pragma unroll
    for (int k=0;k<16;k++) B[k]=row[16+k];
    #pragma unroll
    for (int k=0;k<16;k++) C[k]=row[32+k];
    #pragma unroll
    for (int k=0;k<16;k++) D[k]=row[48+k];
    float s = 0.f;
    #pragma unroll 1
    for (int it=0; it<16; it++){
        int b0 = it*64;
        #pragma unroll
        for (int k=0;k<16;k++){
            float4 a4 = avs4[b0+k]; float4 v = A[k];
            s=fmaf(a4.x,v.x,s); s=fmaf(a4.y,v.y,s); s=fmaf(a4.z,v.z,s); s=fmaf(a4.w,v.w,s);
        }
        if (it<15){
            #pragma unroll
            for (int k=0;k<16;k++) A[k]=row[b0+64+k];
        }
        #pragma unroll
        for (int k=0;k<16;k++){
            float4 a4 = avs4[b0+16+k]; float4 v = B[k];
            s=fmaf(a4.x,v.x,s); s=fmaf(a4.y,v.y,s); s=fmaf(a4.z,v.z,s); s=fmaf(a4.w,v.w,s);
        }
        if (it<15){
            #pragma unroll
            for (int k=0;k<16;k++) B[k]=row[b0+80+k];
        }
        #pragma unroll
        for (int k=0;k<16;k++){
            float4 a4 = avs4[b0+32+k]; float4 v = C[k];
            s=fmaf(a4.x,v.x,s); s=fmaf(a4.y,v.y,s); s=fmaf(a4.z,v.z,s); s=fmaf(a4.w,v.w,s);
        }
        if (it<15){
            #pragma unroll
            for (int k=0;k<16;k++) C[k]=row[b0+96+k];
        }
        #pragma unroll
        for (int k=0;k<16;k++){
            float4 a4 = avs4[b0+48+k]; float4 v = D[k];
            s=fmaf(a4.x,v.x,s); s=fmaf(a4.y,v.y,s); s=fmaf(a4.z,v.z,s); s=fmaf(a4.w,v.w,s);
        }
        if (it<15){
            #pragma unroll
            for (int k=0;k<16;k++) D[k]=row[b0+112+k];
        }
    }
    kta[j] = s;
    bv[j]  = MU_S/(s + TINY);
}

// leaf sums of pi_s_new = (a*K)*b — np two-step rounding
__global__ __launch_bounds__(64) void k_leafs_pisnew(const float* __restrict__ K,
        const float* __restrict__ av, const float* __restrict__ bv, float* __restrict__ leafS){
    int lane = threadIdx.x;
    int row  = blockIdx.x*2 + (lane>>5);
    int L    = lane & 31;
    float a  = av[row];
    const float* Kr = K + (size_t)row*NROW + L*128;
    const float* br = bv + L*128;
    float r0,r1,r2,r3,r4,r5,r6,r7;
    r0=sepf((a*Kr[0])*br[0]); r1=sepf((a*Kr[1])*br[1]);
    r2=sepf((a*Kr[2])*br[2]); r3=sepf((a*Kr[3])*br[3]);
    r4=sepf((a*Kr[4])*br[4]); r5=sepf((a*Kr[5])*br[5]);
    r6=sepf((a*Kr[6])*br[6]); r7=sepf((a*Kr[7])*br[7]);
    #pragma unroll
    for (int i=8;i<128;i+=8){
        r0+=sepf((a*Kr[i+0])*br[i+0]); r1+=sepf((a*Kr[i+1])*br[i+1]);
        r2+=sepf((a*Kr[i+2])*br[i+2]); r3+=sepf((a*Kr[i+3])*br[i+3]);
        r4+=sepf((a*Kr[i+4])*br[i+4]); r5+=sepf((a*Kr[i+5])*br[i+5]);
        r6+=sepf((a*Kr[i+6])*br[i+6]); r7+=sepf((a*Kr[i+7])*br[i+7]);
    }
    leafS[row*32 + L] = ((r0+r1)+(r2+r3)) + ((r4+r5)+(r6+r7));
}

__global__ __launch_bounds__(128) void k_tree1(const float* __restrict__ leafS,
        float* __restrict__ part){
    __shared__ float ld[256];
    int t = threadIdx.x, g = blockIdx.x;
    ld[t]     = leafS[g*256 + t];
    ld[t+128] = leafS[g*256 + t + 128];
    __syncthreads();
    for (int h=128; h>=1; h>>=1){
        if (t<h) ld[t] = ld[2*t] + ld[2*t+1];
        __syncthreads();
    }
    if (t==0) part[g] = ld[0];
}

template<int MODE>
__global__ __launch_bounds__(256) void k_tree2(const float* __restrict__ part,
        float* __restrict__ scal){
    __shared__ float ld[512];
    int t = threadIdx.x;
    ld[t]     = part[t];
    ld[t+256] = part[t+256];
    __syncthreads();
    for (int h=256; h>=1; h>>=1){
        if (t<h) ld[t] = ld[2*t] + ld[2*t+1];
        __syncthreads();
    }
    if (t==0){
        float S = ld[0];
        if (MODE==0) scal[4] = scal[0]/(S + TINY);
        else         scal[5] = S;
    }
}

// in place: K -> pi_s = ((a*K)*b)*ratio  (final mul feeds a STORE -> safe)
__global__ void k_finalize(float* __restrict__ K, const float* __restrict__ av,
        const float* __restrict__ bv, const float* __restrict__ scal){
    float ratio = scal[4];
    int stride = gridDim.x*blockDim.x;
    for (int idx = blockIdx.x*blockDim.x+threadIdx.x; idx < NROW*NROW; idx += stride){
        int row = idx >> 12, col = idx & 4095;
        K[idx] = ((av[row]*K[idx])*bv[col])*ratio;
    }
}

// row sums of pi_s (np pairwise: 32 leaves + balanced xor tree) + leafS for total
__global__ __launch_bounds__(64) void k_rows_np(const float* __restrict__ P,
        float* __restrict__ rsf, float* __restrict__ leafS){
    int lane = threadIdx.x;
    int row  = blockIdx.x*2 + (lane>>5);
    int L    = lane & 31;
    float leaf = np_leaf128(P + (size_t)row*NROW + L*128);
    leafS[row*32 + L] = leaf;
    float s = leaf;
    s += __shfl_xor(s, 1);
    s += __shfl_xor(s, 2);
    s += __shfl_xor(s, 4);
    s += __shfl_xor(s, 8);
    s += __shfl_xor(s, 16);
    if (L==0) rsf[row] = s;
}

// fallback col sums of pi_s
__global__ __launch_bounds__(256) void k_cols_np(const float* __restrict__ P,
        float* __restrict__ csf){
    int j = blockIdx.x*256 + threadIdx.x;
    float s = P[j];
    #pragma unroll 4
    for (int i=1;i<NROW;i++) s += P[(size_t)i*NROW + j];
    csf[j] = s;
}

// fast col sums: recompute pi_s from K^T (bit-identical mul chain).
// sepf() REQUIRED: without it the compiler fuses *ratio into the add (fmaf),
// skipping the rounding that k_finalize applied -> R8's absmax drift.
__global__ __launch_bounds__(64) void k_cols_fast(const float* __restrict__ KT,
        const float* __restrict__ av, const float* __restrict__ bv,
        const float* __restrict__ scal, float* __restrict__ csf){
    int j = blockIdx.x*64 + threadIdx.x;
    float b = bv[j], ratio = scal[4];
    const float4* row = reinterpret_cast<const float4*>(KT + (size_t)j*NROW);
    float s = 0.f;
    #pragma unroll 8
    for (int i4=0; i4<1024; i4++){
        float4 kv = row[i4];
        s += sepf(((av[i4*4+0]*kv.x)*b)*ratio);
        s += sepf(((av[i4*4+1]*kv.y)*b)*ratio);
        s += sepf(((av[i4*4+2]*kv.z)*b)*ratio);
        s += sepf(((av[i4*4+3]*kv.w)*b)*ratio);
    }
    csf[j] = s;
}

// t_f[k] = (X*X).T @ r : sgemv_n = sequential over i, single acc per k
__global__ __launch_bounds__(128) void k_tvec_f(const float* __restrict__ M,
        const float* __restrict__ r, float* __restrict__ out){
    int k = threadIdx.x;
    float s = 0.f;
    #pragma unroll 8
    for (int i=0;i<NROW;i++){
        float x = M[(size_t)i*DFEAT + k];
        float xx = x*x;
        s = fmaf(xx, r[i], s);
    }
    out[k] = s;
}

// fallback U = X^T @ pi_s (kc=384 block partials)
__global__ __launch_bounds__(256) void k_U(const float* __restrict__ X,
        const float* __restrict__ P, float* __restrict__ U){
    int o = blockIdx.x*256 + threadIdx.x;
    int j = o & 4095, k = o >> 12;
    float acc = 0.f;
    for (int t=0; t<11; t++){
        int i0 = t*384;
        int len = (i0+384 <= NROW) ? 384 : (NROW - i0);
        float part = 0.f;
        #pragma unroll 4
        for (int q=0;q<len;q++)
            part = fmaf(X[(size_t)(i0+q)*DFEAT + k], P[(size_t)(i0+q)*NROW + j], part);
        acc = (t==0) ? part : acc + part;
    }
    U[(size_t)k*NROW + j] = acc;
}

// fast U: pi_s recomputed from K^T stream ('p' feeds a MUL -> contraction-safe)
__global__ __launch_bounds__(64) void k_U_fast(const float* __restrict__ X,
        const float* __restrict__ KT, const float* __restrict__ av,
        const float* __restrict__ bv, const float* __restrict__ scal,
        float* __restrict__ U){
    int j  = (blockIdx.x >> 3)*64 + threadIdx.x;
    int k0 = (blockIdx.x & 7)*16;
    float b = bv[j], ratio = scal[4];
    const float* ktrow = KT + (size_t)j*NROW;
    float acc[16];
    for (int t=0; t<11; t++){
        int i0 = t*384;
        int len = (i0+384 <= NROW) ? 384 : (NROW - i0);
        float part[16];
        #pragma unroll
        for (int d=0;d<16;d++) part[d]=0.f;
        #pragma unroll 4
        for (int q=0;q<len;q++){
            float kt = ktrow[i0+q];
            float p  = ((av[i0+q]*kt)*b)*ratio;   // == pi_s[i0+q][j] bit-exact
            const float* xr = X + (size_t)(i0+q)*DFEAT + k0;
            #pragma unroll
            for (int d=0;d<16;d++) part[d] = fmaf(xr[d], p, part[d]);
        }
        #pragma unroll
        for (int d=0;d<16;d++) acc[d] = (t==0)? part[d] : acc[d]+part[d];
    }
    #pragma unroll
    for (int d=0;d<16;d++) U[(size_t)(k0+d)*NROW + j] = acc[d];
}

// V = U @ Y ; C_f = (t1f+t2f) + (-2*V)
__global__ __launch_bounds__(256) void k_V(const float* __restrict__ U,
        const float* __restrict__ Y, const float* __restrict__ t1f,
        const float* __restrict__ t2f, float* __restrict__ Cf){
    int o = blockIdx.x*256 + threadIdx.x;   // 16384
    int k = o >> 7, l = o & 127;
    float acc = 0.f;
    for (int t=0; t<11; t++){
        int j0 = t*384;
        int len = (j0+384 <= NROW) ? 384 : (NROW - j0);
        float part = 0.f;
        #pragma unroll 4
        for (int q=0;q<len;q++)
            part = fmaf(U[(size_t)k*NROW + j0+q], Y[(size_t)(j0+q)*DFEAT + l], part);
        acc = (t==0) ? part : acc + part;
    }
    float t12 = t1f[k] + t2f[l];
    Cf[o] = t12 + (-2.0f*acc);   // *2 exact -> safe
}

// feature Sinkhorn, np-kernel-exact, 100 iters; writes pi_f
__global__ __launch_bounds__(128) void k_sinkhorn_f_np(const float* __restrict__ Cf,
        const float* __restrict__ scal, float* __restrict__ pif){
    __shared__ float kf[128][129];
    __shared__ float a_s[128], b_s[128];
    __shared__ float red[128];
    __shared__ float cmin_sh, safe_sh, flag_sh, fsc_sh;
    int t = threadIdx.x;
    for (int idx=t; idx<16384; idx+=128) kf[idx>>7][idx&127] = Cf[idx];
    __syncthreads();
    float mn = kf[t][0], mx = kf[t][0];
    for (int c=1;c<128;c++){ float v=kf[t][c]; mn=fminf(mn,v); mx=fmaxf(mx,v); }
    red[t]=mn; __syncthreads();
    for (int s=64;s;s>>=1){ if(t<s) red[t]=fminf(red[t],red[t+s]); __syncthreads(); }
    if (t==0) cmin_sh = red[0];
    __syncthreads();
    red[t]=mx; __syncthreads();
    for (int s=64;s;s>>=1){ if(t<s) red[t]=fmaxf(red[t],red[t+s]); __syncthreads(); }
    if (t==0){
        float scale = red[0] - cmin_sh;
        safe_sh = (scale>1e-8f)? scale : 1.0f;
        flag_sh = (scale>1e-8f)? 1.0f  : 0.0f;
    }
    __syncthreads();
    float cmin=cmin_sh, safe=safe_sh, flag=flag_sh;
    for (int c=0;c<128;c++){
        if (flag > 0.5f){
            float sub = kf[t][c] - cmin;
            float cn  = sub / safe;
            float arg = (-cn) / EPS32;
            kf[t][c]  = (float)exp((double)arg);
        } else kf[t][c] = 1.0f;
    }
    b_s[t] = 1.0f;
    __syncthreads();
    float x[128];
    #pragma unroll 4
    for (int c=0;c<128;c++) x[c] = kf[t][c];
    for (int it=0; it<100; it++){
        float kb = blas_dot128(x, b_s);
        a_s[t] = MU_F/(kb + TINY);
        __syncthreads();
        float s = 0.f;
        #pragma unroll 4
        for (int i=0;i<128;i++) s = fmaf(a_s[i], kf[i][t], s);
        b_s[t] = MU_F/(s + TINY);
        __syncthreads();
    }
    float ar = a_s[t];
    float e[128];
    #pragma unroll 4
    for (int c=0;c<128;c++) e[c] = sepf((ar*x[c])*b_s[c]);
    {
        float r0=e[0],r1=e[1],r2=e[2],r3=e[3],r4=e[4],r5=e[5],r6=e[6],r7=e[7];
        #pragma unroll
        for (int i=8;i<128;i+=8){
            r0+=e[i+0]; r1+=e[i+1]; r2+=e[i+2]; r3+=e[i+3];
            r4+=e[i+4]; r5+=e[i+5]; r6+=e[i+6]; r7+=e[i+7];
        }
        red[t] = ((r0+r1)+(r2+r3)) + ((r4+r5)+(r6+r7));
    }
    __syncthreads();
    for (int h=64; h>=1; h>>=1){
        if (t<h) red[t] = red[2*t] + red[2*t+1];
        __syncthreads();
    }
    if (t==0) fsc_sh = scal[5]/(red[0] + TINY);
    __syncthreads();
    float fsc = fsc_sh;
    #pragma unroll 4
    for (int c=0;c<128;c++) pif[t*DFEAT + c] = e[c]*fsc;
}

extern "C" void kernel_launch(void* const* d_in, const int* in_sizes, int n_in,
                              void* d_out, int out_size, void* d_ws, size_t ws_size,
                              hipStream_t stream){
    const float* X = (const float*)d_in[0];
    const float* Y = (const float*)d_in[1];
    float* out  = (float*)d_out;
    float* Kmat = out;                        // C -> K -> pi_s in place
    float* pif  = out + (size_t)NROW*NROW;    // pi_f (state + output 1)
    float* w = (float*)d_ws;
    float* W      = w;                        // 524288
    float* U      = W      + 524288;          // 524288
    float* leafS  = U      + 524288;          // 131072
    float* part   = leafS  + 131072;          // 512
    float* av     = part   + 512;
    float* bv     = av     + 4096;
    float* kta    = bv     + 4096;
    float* rsf    = kta    + 4096;
    float* csf    = rsf    + 4096;
    float* t1     = csf    + 4096;
    float* t2     = t1     + 4096;
    float* bmin   = t2     + 4096;            // 65536
    float* bmax   = bmin   + 65536;           // 65536
    float* rvec   = bmax   + 65536;
    float* cvec   = rvec   + 128;
    float* t1f    = cvec   + 128;
    float* t2f    = t1f    + 128;
    float* Cf     = t2f    + 128;             // 16384
    float* scal   = Cf     + 16384;           // 16
    float* KT     = scal   + 16;              // 16777216 (64 MB), fast path only
    size_t need_floats = (size_t)(KT - w) + (size_t)NROW*NROW;
    bool hasKT = ws_size >= need_floats*sizeof(float);

    k_fill<<<64, 256, 0, stream>>>(pif, 16384, 1.0f/16384.0f);   // 2^-14 exact
    for (int outer=0; outer<5; outer++){
        k_pifsums<<<1, 128, 0, stream>>>(pif, rvec, cvec, scal);
        k_tvec<<<128, 256, 0, stream>>>(X, rvec, t1);
        k_tvec<<<128, 256, 0, stream>>>(Y, cvec, t2);
        k_gemm_w<<<2048, 256, 0, stream>>>(X, pif, W);
        k_gemm_c<<<dim3(256,256), 256, 0, stream>>>(W, Y, t1, t2, Kmat, bmin, bmax);
        k_minmax<<<1, 256, 0, stream>>>(bmin, bmax, 65536, scal);
        if (hasKT) k_exp_t<<<dim3(64,64), 256, 0, stream>>>(Kmat, KT, scal);
        else       k_exp<<<2048, 256, 0, stream>>>(Kmat, scal);
        k_fill<<<16, 256, 0, stream>>>(bv, 4096, 1.0f);
        for (int it=0; it<100; it++){
            k_kb_np<<<512, 64, 0, stream>>>(Kmat, bv, av);
            if (hasKT) k_kta_fast<<<64, 64, 0, stream>>>(KT, av, kta, bv);
            else       k_kta_np<<<16, 256, 0, stream>>>(Kmat, av, kta, bv);
        }
        k_leafs_pisnew<<<2048, 64, 0, stream>>>(Kmat, av, bv, leafS);
        k_tree1<<<512, 128, 0, stream>>>(leafS, part);
        k_tree2<0><<<1, 256, 0, stream>>>(part, scal);           // ratio_s
        k_finalize<<<2048, 256, 0, stream>>>(Kmat, av, bv, scal);// K -> pi_s
        k_rows_np<<<2048, 64, 0, stream>>>(Kmat, rsf, leafS);
        k_tree1<<<512, 128, 0, stream>>>(leafS, part);
        k_tree2<1><<<1, 256, 0, stream>>>(part, scal);           // pis_total
        if (hasKT) k_cols_fast<<<64, 64, 0, stream>>>(KT, av, bv, scal, csf);
        else       k_cols_np<<<16, 256, 0, stream>>>(Kmat, csf);
        k_tvec_f<<<1, 128, 0, stream>>>(X, rsf, t1f);
        k_tvec_f<<<1, 128, 0, stream>>>(Y, csf, t2f);
        if (hasKT) k_U_fast<<<512, 64, 0, stream>>>(X, KT, av, bv, scal, U);
        else       k_U<<<2048, 256, 0, stream>>>(X, Kmat, U);
        k_V<<<64, 256, 0, stream>>>(U, Y, t1f, t2f, Cf);
        k_sinkhorn_f_np<<<1, 128, 0, stream>>>(Cf, scal, pif);
    }
}

// Round 10
// 69549.402 us; speedup vs baseline: 1.6301x; 1.6301x over previous
//
#include <hip/hip_runtime.h>
#include <math.h>
#include <cfloat>

#define NROW 4096
#define DFEAT 128
constexpr float EPS32   = 0.01f;
constexpr float GAMMA32 = (float)(5.0/5.01);   // f32(rho/(rho+eps))
constexpr float MU_S    = 1.0f/4096.0f;
constexpr float MU_F    = 1.0f/128.0f;
constexpr float TINY    = 1e-16f;

// scal: 0=pif_sum 1=cmin 2=safe 3=flag 4=ratio_s 5=pis_total

// rounding barrier: blocks -ffp-contract=fast from fusing mul into a later add
__device__ __forceinline__ float sepf(float x){ asm volatile("" : "+v"(x)); return x; }

// ---------- numpy/OpenBLAS-exact helpers ----------

// numpy pairwise leaf: 128 contiguous values, 8 accumulators, plain adds
__device__ __forceinline__ float np_leaf128(const float* a){
    float r0=a[0],r1=a[1],r2=a[2],r3=a[3],r4=a[4],r5=a[5],r6=a[6],r7=a[7];
    #pragma unroll
    for (int i=8;i<128;i+=8){
        r0+=a[i+0]; r1+=a[i+1]; r2+=a[i+2]; r3+=a[i+3];
        r4+=a[i+4]; r5+=a[i+5]; r6+=a[i+6]; r7+=a[i+7];
    }
    return ((r0+r1)+(r2+r3)) + ((r4+r5)+(r6+r7));
}

// OpenBLAS sgemv_t dot, length 128: ONE 8-lane ymm acc, stride-8
__device__ __forceinline__ float blas_dot128(const float* x, const float* y){
    float acc[8];
    #pragma unroll
    for (int p=0;p<8;p++) acc[p]=0.f;
    #pragma unroll
    for (int m=0;m<16;m++)
        #pragma unroll
        for (int p=0;p<8;p++) acc[p] = fmaf(x[m*8+p], y[m*8+p], acc[p]);
    float s0=acc[0]+acc[4], s1=acc[1]+acc[5], s2=acc[2]+acc[6], s3=acc[3]+acc[7];
    return (s0+s1)+(s2+s3);
}

// ---------- kernels ----------

__global__ void k_fill(float* __restrict__ p, int n, float v){
    int i = blockIdx.x*blockDim.x + threadIdx.x;
    if (i < n) p[i] = v;
}

__global__ __launch_bounds__(128) void k_pifsums(const float* __restrict__ pif,
        float* __restrict__ rvec, float* __restrict__ cvec, float* __restrict__ scal){
    int t = threadIdx.x;
    float rs = np_leaf128(pif + t*DFEAT);
    rvec[t] = rs;
    float cs = pif[t];
    for (int i=1;i<DFEAT;i++) cs += pif[i*DFEAT + t];
    cvec[t] = cs;
    __shared__ float ld[128];
    ld[t] = rs; __syncthreads();
    for (int h=64; h>=1; h>>=1){
        if (t<h) ld[t] = ld[2*t] + ld[2*t+1];
        __syncthreads();
    }
    if (t==0) scal[0] = ld[0];
}

// t1[i] = (X*X)[i,:] @ r — sgemv_t: 8 lanes stride-8 + blas hsum
__global__ __launch_bounds__(256) void k_tvec(const float* __restrict__ M,
        const float* __restrict__ r, float* __restrict__ out){
    int row = blockIdx.x*32 + (threadIdx.x >> 3);
    int p   = threadIdx.x & 7;
    const float* mr = M + (size_t)row*DFEAT;
    float acc = 0.f;
    #pragma unroll
    for (int m=0;m<16;m++){
        float x = mr[p + 8*m];
        float xx = x*x;
        acc = fmaf(xx, r[p + 8*m], acc);
    }
    acc += __shfl_xor(acc, 4);
    acc += __shfl_xor(acc, 1);
    acc += __shfl_xor(acc, 2);
    if (p==0) out[row] = acc;
}

// W = X @ pi_f : per-output sequential k-chain
__global__ __launch_bounds__(256) void k_gemm_w(const float* __restrict__ X,
        const float* __restrict__ pif, float* __restrict__ W){
    int o = blockIdx.x*256 + threadIdx.x;
    int i = o >> 7, j = o & 127;
    const float* xr = X + (size_t)i*DFEAT;
    float acc = 0.f;
    #pragma unroll 8
    for (int k=0;k<DFEAT;k++) acc = fmaf(xr[k], pif[k*DFEAT + j], acc);
    W[o] = acc;
}

// C = (t1+t2) + (-2 * W@Y^T); per-output sequential k-chain; block min/max
__global__ __launch_bounds__(256) void k_gemm_c(const float* __restrict__ W, const float* __restrict__ Y,
        const float* __restrict__ t1, const float* __restrict__ t2,
        float* __restrict__ C, float* __restrict__ bmin, float* __restrict__ bmax){
    __shared__ float Ws[16][132];
    __shared__ float Ys[16][132];
    int t = threadIdx.x;
    int bi = blockIdx.y, bj = blockIdx.x;
    for (int l=t; l<2048; l+=256){
        int r = l>>7, k = l&127;
        Ws[r][k] = W[(size_t)(bi*16+r)*DFEAT + k];
        Ys[r][k] = Y[(size_t)(bj*16+r)*DFEAT + k];
    }
    __syncthreads();
    int a = t >> 4, b = t & 15;
    float acc = 0.f;
    #pragma unroll 8
    for (int k=0;k<DFEAT;k++) acc = fmaf(Ws[a][k], Ys[b][k], acc);
    int gi = bi*16 + a, gj = bj*16 + b;
    float t12 = t1[gi] + t2[gj];
    float v   = t12 + (-2.0f*acc);   // *2 exact -> contraction-safe
    C[(size_t)gi*NROW + gj] = v;
    __shared__ float rmn[256], rmx[256];
    rmn[t]=v; rmx[t]=v; __syncthreads();
    for (int s=128;s;s>>=1){
        if (t<s){ rmn[t]=fminf(rmn[t],rmn[t+s]); rmx[t]=fmaxf(rmx[t],rmx[t+s]); }
        __syncthreads();
    }
    if (t==0){ int bid = bi*gridDim.x + bj; bmin[bid]=rmn[0]; bmax[bid]=rmx[0]; }
}

__global__ void k_minmax(const float* __restrict__ bmin, const float* __restrict__ bmax,
                         int n, float* __restrict__ scal){
    int t = threadIdx.x; // 256
    float mn=FLT_MAX, mx=-FLT_MAX;
    for (int i=t;i<n;i+=256){ mn=fminf(mn,bmin[i]); mx=fmaxf(mx,bmax[i]); }
    __shared__ float rmn[256], rmx[256];
    rmn[t]=mn; rmx[t]=mx; __syncthreads();
    for (int s=128;s;s>>=1){
        if (t<s){ rmn[t]=fminf(rmn[t],rmn[t+s]); rmx[t]=fmaxf(rmx[t],rmx[t+s]); }
        __syncthreads();
    }
    if (t==0){
        float cmin=rmn[0], scale=rmx[0]-rmn[0];
        scal[1]=cmin;
        scal[2]=(scale>1e-8f)? scale : 1.0f;
        scal[3]=(scale>1e-8f)? 1.0f  : 0.0f;
    }
}

// K = exp((-((C-cmin)/safe))/0.01f) — fallback (no transpose)
__global__ void k_exp(float* __restrict__ K, const float* __restrict__ scal){
    float cmin=scal[1], safe=scal[2], flag=scal[3];
    int stride = gridDim.x*blockDim.x;
    for (int i = blockIdx.x*blockDim.x+threadIdx.x; i < NROW*NROW; i += stride){
        if (flag > 0.5f){
            float sub = K[i] - cmin;
            float cn  = sub / safe;
            float arg = (-cn) / EPS32;
            K[i] = (float)exp((double)arg);
        } else {
            K[i] = 1.0f;
        }
    }
}

// fast path: K = exp(...) in place AND K^T written to KT (LDS-tiled transpose)
__global__ __launch_bounds__(256) void k_exp_t(float* __restrict__ K, float* __restrict__ KT,
        const float* __restrict__ scal){
    __shared__ float tile[64][65];
    float cmin=scal[1], safe=scal[2], flag=scal[3];
    int bi = blockIdx.y, bj = blockIdx.x;
    int t = threadIdx.x;
    for (int l=t; l<4096; l+=256){
        int r = l>>6, c = l&63;
        size_t idx = (size_t)(bi*64+r)*NROW + bj*64+c;
        float v = K[idx];
        if (flag > 0.5f){
            float sub = v - cmin;
            float cn  = sub / safe;
            float arg = (-cn) / EPS32;
            v = (float)exp((double)arg);
        } else v = 1.0f;
        K[idx] = v;
        tile[c][r] = v;
    }
    __syncthreads();
    for (int l=t; l<4096; l+=256){
        int r = l>>6, c = l&63;
        KT[(size_t)(bj*64+r)*NROW + bi*64+c] = tile[r][c];
    }
}

// a = (mu/(K@b+1e-16))^gamma ; sgemv_t: 8-lane stride-8, blas hsum; 16 rows/block
// (R8's known-good shape: 256 blocks x 128 threads, direct bv reads)
__global__ __launch_bounds__(128) void k_kb_np(const float* __restrict__ K,
        const float* __restrict__ bv, float* __restrict__ av){
    int row = blockIdx.x*16 + (threadIdx.x >> 3);
    int p   = threadIdx.x & 7;
    const float* Kr = K + (size_t)row*NROW;
    float acc = 0.f;
    #pragma unroll 16
    for (int m=0;m<512;m++) acc = fmaf(Kr[p+8*m], bv[p+8*m], acc);
    acc += __shfl_xor(acc, 4);
    acc += __shfl_xor(acc, 1);
    acc += __shfl_xor(acc, 2);
    if (p==0){
        float den = acc + TINY;
        float q   = MU_S / den;
        av[row] = (float)pow((double)q, (double)GAMMA32);
    }
}

// fallback kta (column walk over K)
__global__ __launch_bounds__(256) void k_kta_np(const float* __restrict__ K,
        const float* __restrict__ av, float* __restrict__ kta, float* __restrict__ bv){
    int j = blockIdx.x*256 + threadIdx.x;
    float s = 0.f;
    #pragma unroll 4
    for (int i=0;i<NROW;i++) s = fmaf(av[i], K[(size_t)i*NROW + j], s);
    kta[j] = s;
    bv[j]  = MU_S/(s + TINY);
}

// fast kta: 4 columns per 256-thread block (grid 1024 -> all CUs busy).
// K^T rows + av staged in LDS coalesced; lane 0 of each wave runs numpy's
// exact serial 4096-FMA chain from LDS (bit-identical order).
__global__ __launch_bounds__(256) void k_kta_blk(const float* __restrict__ KT,
        const float* __restrict__ av, float* __restrict__ kta, float* __restrict__ bv){
    __shared__ float buf[4][NROW];
    __shared__ float avs[NROW];
    int t = threadIdx.x;
    int j0 = blockIdx.x*4;
    {
        const float4* av4 = reinterpret_cast<const float4*>(av);
        float4* a4 = reinterpret_cast<float4*>(avs);
        #pragma unroll
        for (int i=t;i<1024;i+=256) a4[i] = av4[i];
        #pragma unroll
        for (int c=0;c<4;c++){
            const float4* r4 = reinterpret_cast<const float4*>(KT + (size_t)(j0+c)*NROW);
            float4* b4 = reinterpret_cast<float4*>(&buf[c][0]);
            #pragma unroll
            for (int i=t;i<1024;i+=256) b4[i] = r4[i];
        }
    }
    __syncthreads();
    int w = t >> 6, lane = t & 63;
    if (lane==0){
        const float* bc = &buf[w][0];
        float s = 0.f;
        #pragma unroll 8
        for (int i=0;i<NROW;i++) s = fmaf(avs[i], bc[i], s);
        int j = j0 + w;
        kta[j] = s;
        bv[j]  = MU_S/(s + TINY);
    }
}

// leaf sums of pi_s_new = (a*K)*b — np two-step rounding
__global__ __launch_bounds__(64) void k_leafs_pisnew(const float* __restrict__ K,
        const float* __restrict__ av, const float* __restrict__ bv, float* __restrict__ leafS){
    int lane = threadIdx.x;
    int row  = blockIdx.x*2 + (lane>>5);
    int L    = lane & 31;
    float a  = av[row];
    const float* Kr = K + (size_t)row*NROW + L*128;
    const float* br = bv + L*128;
    float r0,r1,r2,r3,r4,r5,r6,r7;
    r0=sepf((a*Kr[0])*br[0]); r1=sepf((a*Kr[1])*br[1]);
    r2=sepf((a*Kr[2])*br[2]); r3=sepf((a*Kr[3])*br[3]);
    r4=sepf((a*Kr[4])*br[4]); r5=sepf((a*Kr[5])*br[5]);
    r6=sepf((a*Kr[6])*br[6]); r7=sepf((a*Kr[7])*br[7]);
    #pragma unroll
    for (int i=8;i<128;i+=8){
        r0+=sepf((a*Kr[i+0])*br[i+0]); r1+=sepf((a*Kr[i+1])*br[i+1]);
        r2+=sepf((a*Kr[i+2])*br[i+2]); r3+=sepf((a*Kr[i+3])*br[i+3]);
        r4+=sepf((a*Kr[i+4])*br[i+4]); r5+=sepf((a*Kr[i+5])*br[i+5]);
        r6+=sepf((a*Kr[i+6])*br[i+6]); r7+=sepf((a*Kr[i+7])*br[i+7]);
    }
    leafS[row*32 + L] = ((r0+r1)+(r2+r3)) + ((r4+r5)+(r6+r7));
}

__global__ __launch_bounds__(128) void k_tree1(const float* __restrict__ leafS,
        float* __restrict__ part){
    __shared__ float ld[256];
    int t = threadIdx.x, g = blockIdx.x;
    ld[t]     = leafS[g*256 + t];
    ld[t+128] = leafS[g*256 + t + 128];
    __syncthreads();
    for (int h=128; h>=1; h>>=1){
        if (t<h) ld[t] = ld[2*t] + ld[2*t+1];
        __syncthreads();
    }
    if (t==0) part[g] = ld[0];
}

template<int MODE>
__global__ __launch_bounds__(256) void k_tree2(const float* __restrict__ part,
        float* __restrict__ scal){
    __shared__ float ld[512];
    int t = threadIdx.x;
    ld[t]     = part[t];
    ld[t+256] = part[t+256];
    __syncthreads();
    for (int h=256; h>=1; h>>=1){
        if (t<h) ld[t] = ld[2*t] + ld[2*t+1];
        __syncthreads();
    }
    if (t==0){
        float S = ld[0];
        if (MODE==0) scal[4] = scal[0]/(S + TINY);
        else         scal[5] = S;
    }
}

// in place: K -> pi_s = ((a*K)*b)*ratio  (final mul feeds a STORE -> safe)
__global__ void k_finalize(float* __restrict__ K, const float* __restrict__ av,
        const float* __restrict__ bv, const float* __restrict__ scal){
    float ratio = scal[4];
    int stride = gridDim.x*blockDim.x;
    for (int idx = blockIdx.x*blockDim.x+threadIdx.x; idx < NROW*NROW; idx += stride){
        int row = idx >> 12, col = idx & 4095;
        K[idx] = ((av[row]*K[idx])*bv[col])*ratio;
    }
}

// row sums of pi_s (np pairwise: 32 leaves + balanced xor tree) + leafS for total
__global__ __launch_bounds__(64) void k_rows_np(const float* __restrict__ P,
        float* __restrict__ rsf, float* __restrict__ leafS){
    int lane = threadIdx.x;
    int row  = blockIdx.x*2 + (lane>>5);
    int L    = lane & 31;
    float leaf = np_leaf128(P + (size_t)row*NROW + L*128);
    leafS[row*32 + L] = leaf;
    float s = leaf;
    s += __shfl_xor(s, 1);
    s += __shfl_xor(s, 2);
    s += __shfl_xor(s, 4);
    s += __shfl_xor(s, 8);
    s += __shfl_xor(s, 16);
    if (L==0) rsf[row] = s;
}

// fallback col sums of pi_s
__global__ __launch_bounds__(256) void k_cols_np(const float* __restrict__ P,
        float* __restrict__ csf){
    int j = blockIdx.x*256 + threadIdx.x;
    float s = P[j];
    #pragma unroll 4
    for (int i=1;i<NROW;i++) s += P[(size_t)i*NROW + j];
    csf[j] = s;
}

// fast col sums: recompute pi_s from K^T (bit-identical mul chain).
// sepf() REQUIRED: without it the compiler fuses *ratio into the add (fmaf),
// skipping the rounding that k_finalize applied -> R8's absmax drift.
__global__ __launch_bounds__(64) void k_cols_fast(const float* __restrict__ KT,
        const float* __restrict__ av, const float* __restrict__ bv,
        const float* __restrict__ scal, float* __restrict__ csf){
    int j = blockIdx.x*64 + threadIdx.x;
    float b = bv[j], ratio = scal[4];
    const float4* row = reinterpret_cast<const float4*>(KT + (size_t)j*NROW);
    float s = 0.f;
    #pragma unroll 8
    for (int i4=0; i4<1024; i4++){
        float4 kv = row[i4];
        s += sepf(((av[i4*4+0]*kv.x)*b)*ratio);
        s += sepf(((av[i4*4+1]*kv.y)*b)*ratio);
        s += sepf(((av[i4*4+2]*kv.z)*b)*ratio);
        s += sepf(((av[i4*4+3]*kv.w)*b)*ratio);
    }
    csf[j] = s;
}

// t_f[k] = (X*X).T @ r : sgemv_n = sequential over i, single acc per k
__global__ __launch_bounds__(128) void k_tvec_f(const float* __restrict__ M,
        const float* __restrict__ r, float* __restrict__ out){
    int k = threadIdx.x;
    float s = 0.f;
    #pragma unroll 8
    for (int i=0;i<NROW;i++){
        float x = M[(size_t)i*DFEAT + k];
        float xx = x*x;
        s = fmaf(xx, r[i], s);
    }
    out[k] = s;
}

// fallback U = X^T @ pi_s (kc=384 block partials)
__global__ __launch_bounds__(256) void k_U(const float* __restrict__ X,
        const float* __restrict__ P, float* __restrict__ U){
    int o = blockIdx.x*256 + threadIdx.x;
    int j = o & 4095, k = o >> 12;
    float acc = 0.f;
    for (int t=0; t<11; t++){
        int i0 = t*384;
        int len = (i0+384 <= NROW) ? 384 : (NROW - i0);
        float part = 0.f;
        #pragma unroll 4
        for (int q=0;q<len;q++)
            part = fmaf(X[(size_t)(i0+q)*DFEAT + k], P[(size_t)(i0+q)*NROW + j], part);
        acc = (t==0) ? part : acc + part;
    }
    U[(size_t)k*NROW + j] = acc;
}

// fast U: pi_s recomputed from K^T stream ('p' feeds a MUL -> contraction-safe)
__global__ __launch_bounds__(64) void k_U_fast(const float* __restrict__ X,
        const float* __restrict__ KT, const float* __restrict__ av,
        const float* __restrict__ bv, const float* __restrict__ scal,
        float* __restrict__ U){
    int j  = (blockIdx.x >> 3)*64 + threadIdx.x;
    int k0 = (blockIdx.x & 7)*16;
    float b = bv[j], ratio = scal[4];
    const float* ktrow = KT + (size_t)j*NROW;
    float acc[16];
    for (int t=0; t<11; t++){
        int i0 = t*384;
        int len = (i0+384 <= NROW) ? 384 : (NROW - i0);
        float part[16];
        #pragma unroll
        for (int d=0;d<16;d++) part[d]=0.f;
        #pragma unroll 4
        for (int q=0;q<len;q++){
            float kt = ktrow[i0+q];
            float p  = ((av[i0+q]*kt)*b)*ratio;   // == pi_s[i0+q][j] bit-exact
            const float* xr = X + (size_t)(i0+q)*DFEAT + k0;
            #pragma unroll
            for (int d=0;d<16;d++) part[d] = fmaf(xr[d], p, part[d]);
        }
        #pragma unroll
        for (int d=0;d<16;d++) acc[d] = (t==0)? part[d] : acc[d]+part[d];
    }
    #pragma unroll
    for (int d=0;d<16;d++) U[(size_t)(k0+d)*NROW + j] = acc[d];
}

// V = U @ Y ; C_f = (t1f+t2f) + (-2*V)
__global__ __launch_bounds__(256) void k_V(const float* __restrict__ U,
        const float* __restrict__ Y, const float* __restrict__ t1f,
        const float* __restrict__ t2f, float* __restrict__ Cf){
    int o = blockIdx.x*256 + threadIdx.x;   // 16384
    int k = o >> 7, l = o & 127;
    float acc = 0.f;
    for (int t=0; t<11; t++){
        int j0 = t*384;
        int len = (j0+384 <= NROW) ? 384 : (NROW - j0);
        float part = 0.f;
        #pragma unroll 4
        for (int q=0;q<len;q++)
            part = fmaf(U[(size_t)k*NROW + j0+q], Y[(size_t)(j0+q)*DFEAT + l], part);
        acc = (t==0) ? part : acc + part;
    }
    float t12 = t1f[k] + t2f[l];
    Cf[o] = t12 + (-2.0f*acc);   // *2 exact -> safe
}

// feature Sinkhorn, np-kernel-exact, 100 iters; writes pi_f
__global__ __launch_bounds__(128) void k_sinkhorn_f_np(const float* __restrict__ Cf,
        const float* __restrict__ scal, float* __restrict__ pif){
    __shared__ float kf[128][129];
    __shared__ float a_s[128], b_s[128];
    __shared__ float red[128];
    __shared__ float cmin_sh, safe_sh, flag_sh, fsc_sh;
    int t = threadIdx.x;
    for (int idx=t; idx<16384; idx+=128) kf[idx>>7][idx&127] = Cf[idx];
    __syncthreads();
    float mn = kf[t][0], mx = kf[t][0];
    for (int c=1;c<128;c++){ float v=kf[t][c]; mn=fminf(mn,v); mx=fmaxf(mx,v); }
    red[t]=mn; __syncthreads();
    for (int s=64;s;s>>=1){ if(t<s) red[t]=fminf(red[t],red[t+s]); __syncthreads(); }
    if (t==0) cmin_sh = red[0];
    __syncthreads();
    red[t]=mx; __syncthreads();
    for (int s=64;s;s>>=1){ if(t<s) red[t]=fmaxf(red[t],red[t+s]); __syncthreads(); }
    if (t==0){
        float scale = red[0] - cmin_sh;
        safe_sh = (scale>1e-8f)? scale : 1.0f;
        flag_sh = (scale>1e-8f)? 1.0f  : 0.0f;
    }
    __syncthreads();
    float cmin=cmin_sh, safe=safe_sh, flag=flag_sh;
    for (int c=0;c<128;c++){
        if (flag > 0.5f){
            float sub = kf[t][c] - cmin;
            float cn  = sub / safe;
            float arg = (-cn) / EPS32;
            kf[t][c]  = (float)exp((double)arg);
        } else kf[t][c] = 1.0f;
    }
    b_s[t] = 1.0f;
    __syncthreads();
    float x[128];
    #pragma unroll 4
    for (int c=0;c<128;c++) x[c] = kf[t][c];
    for (int it=0; it<100; it++){
        float kb = blas_dot128(x, b_s);
        a_s[t] = MU_F/(kb + TINY);
        __syncthreads();
        float s = 0.f;
        #pragma unroll 4
        for (int i=0;i<128;i++) s = fmaf(a_s[i], kf[i][t], s);
        b_s[t] = MU_F/(s + TINY);
        __syncthreads();
    }
    float ar = a_s[t];
    float e[128];
    #pragma unroll 4
    for (int c=0;c<128;c++) e[c] = sepf((ar*x[c])*b_s[c]);
    {
        float r0=e[0],r1=e[1],r2=e[2],r3=e[3],r4=e[4],r5=e[5],r6=e[6],r7=e[7];
        #pragma unroll
        for (int i=8;i<128;i+=8){
            r0+=e[i+0]; r1+=e[i+1]; r2+=e[i+2]; r3+=e[i+3];
            r4+=e[i+4]; r5+=e[i+5]; r6+=e[i+6]; r7+=e[i+7];
        }
        red[t] = ((r0+r1)+(r2+r3)) + ((r4+r5)+(r6+r7));
    }
    __syncthreads();
    for (int h=64; h>=1; h>>=1){
        if (t<h) red[t] = red[2*t] + red[2*t+1];
        __syncthreads();
    }
    if (t==0) fsc_sh = scal[5]/(red[0] + TINY);
    __syncthreads();
    float fsc = fsc_sh;
    #pragma unroll 4
    for (int c=0;c<128;c++) pif[t*DFEAT + c] = e[c]*fsc;
}

extern "C" void kernel_launch(void* const* d_in, const int* in_sizes, int n_in,
                              void* d_out, int out_size, void* d_ws, size_t ws_size,
                              hipStream_t stream){
    const float* X = (const float*)d_in[0];
    const float* Y = (const float*)d_in[1];
    float* out  = (float*)d_out;
    float* Kmat = out;                        // C -> K -> pi_s in place
    float* pif  = out + (size_t)NROW*NROW;    // pi_f (state + output 1)
    float* w = (float*)d_ws;
    float* W      = w;                        // 524288
    float* U      = W      + 524288;          // 524288
    float* leafS  = U      + 524288;          // 131072
    float* part   = leafS  + 131072;          // 512
    float* av     = part   + 512;
    float* bv     = av     + 4096;
    float* kta    = bv     + 4096;
    float* rsf    = kta    + 4096;
    float* csf    = rsf    + 4096;
    float* t1     = csf    + 4096;
    float* t2     = t1     + 4096;
    float* bmin   = t2     + 4096;            // 65536
    float* bmax   = bmin   + 65536;           // 65536
    float* rvec   = bmax   + 65536;
    float* cvec   = rvec   + 128;
    float* t1f    = cvec   + 128;
    float* t2f    = t1f    + 128;
    float* Cf     = t2f    + 128;             // 16384
    float* scal   = Cf     + 16384;           // 16
    float* KT     = scal   + 16;              // 16777216 (64 MB), fast path only
    size_t need_floats = (size_t)(KT - w) + (size_t)NROW*NROW;
    bool hasKT = ws_size >= need_floats*sizeof(float);

    k_fill<<<64, 256, 0, stream>>>(pif, 16384, 1.0f/16384.0f);   // 2^-14 exact
    for (int outer=0; outer<5; outer++){
        k_pifsums<<<1, 128, 0, stream>>>(pif, rvec, cvec, scal);
        k_tvec<<<128, 256, 0, stream>>>(X, rvec, t1);
        k_tvec<<<128, 256, 0, stream>>>(Y, cvec, t2);
        k_gemm_w<<<2048, 256, 0, stream>>>(X, pif, W);
        k_gemm_c<<<dim3(256,256), 256, 0, stream>>>(W, Y, t1, t2, Kmat, bmin, bmax);
        k_minmax<<<1, 256, 0, stream>>>(bmin, bmax, 65536, scal);
        if (hasKT) k_exp_t<<<dim3(64,64), 256, 0, stream>>>(Kmat, KT, scal);
        else       k_exp<<<2048, 256, 0, stream>>>(Kmat, scal);
        k_fill<<<16, 256, 0, stream>>>(bv, 4096, 1.0f);
        for (int it=0; it<100; it++){
            k_kb_np<<<256, 128, 0, stream>>>(Kmat, bv, av);
            if (hasKT) k_kta_blk<<<1024, 256, 0, stream>>>(KT, av, kta, bv);
            else       k_kta_np<<<16, 256, 0, stream>>>(Kmat, av, kta, bv);
        }
        k_leafs_pisnew<<<2048, 64, 0, stream>>>(Kmat, av, bv, leafS);
        k_tree1<<<512, 128, 0, stream>>>(leafS, part);
        k_tree2<0><<<1, 256, 0, stream>>>(part, scal);           // ratio_s
        k_finalize<<<2048, 256, 0, stream>>>(Kmat, av, bv, scal);// K -> pi_s
        k_rows_np<<<2048, 64, 0, stream>>>(Kmat, rsf, leafS);
        k_tree1<<<512, 128, 0, stream>>>(leafS, part);
        k_tree2<1><<<1, 256, 0, stream>>>(part, scal);           // pis_total
        if (hasKT) k_cols_fast<<<64, 64, 0, stream>>>(KT, av, bv, scal, csf);
        else       k_cols_np<<<16, 256, 0, stream>>>(Kmat, csf);
        k_tvec_f<<<1, 128, 0, stream>>>(X, rsf, t1f);
        k_tvec_f<<<1, 128, 0, stream>>>(Y, csf, t2f);
        if (hasKT) k_U_fast<<<512, 64, 0, stream>>>(X, KT, av, bv, scal, U);
        else       k_U<<<2048, 256, 0, stream>>>(X, Kmat, U);
        k_V<<<64, 256, 0, stream>>>(U, Y, t1f, t2f, Cf);
        k_sinkhorn_f_np<<<1, 128, 0, stream>>>(Cf, scal, pif);
    }
}

// Round 11
// 40551.196 us; speedup vs baseline: 2.7958x; 1.7151x over previous
//
#include <hip/hip_runtime.h>
#include <math.h>
#include <cfloat>

#define NROW 4096
#define DFEAT 128
constexpr float EPS32   = 0.01f;
constexpr float GAMMA32 = (float)(5.0/5.01);   // f32(rho/(rho+eps))
constexpr float MU_S    = 1.0f/4096.0f;
constexpr float MU_F    = 1.0f/128.0f;
constexpr float TINY    = 1e-16f;

// scal: 0=pif_sum 1=cmin 2=safe 3=flag 4=ratio_s 5=pis_total

// rounding barrier: blocks -ffp-contract=fast from fusing mul into a later add
__device__ __forceinline__ float sepf(float x){ asm volatile("" : "+v"(x)); return x; }

// ---------- numpy/OpenBLAS-exact helpers ----------

// numpy pairwise leaf: 128 contiguous values, 8 accumulators, plain adds
__device__ __forceinline__ float np_leaf128(const float* a){
    float r0=a[0],r1=a[1],r2=a[2],r3=a[3],r4=a[4],r5=a[5],r6=a[6],r7=a[7];
    #pragma unroll
    for (int i=8;i<128;i+=8){
        r0+=a[i+0]; r1+=a[i+1]; r2+=a[i+2]; r3+=a[i+3];
        r4+=a[i+4]; r5+=a[i+5]; r6+=a[i+6]; r7+=a[i+7];
    }
    return ((r0+r1)+(r2+r3)) + ((r4+r5)+(r6+r7));
}

// OpenBLAS sgemv_t dot, length 128: ONE 8-lane ymm acc, stride-8
__device__ __forceinline__ float blas_dot128(const float* x, const float* y){
    float acc[8];
    #pragma unroll
    for (int p=0;p<8;p++) acc[p]=0.f;
    #pragma unroll
    for (int m=0;m<16;m++)
        #pragma unroll
        for (int p=0;p<8;p++) acc[p] = fmaf(x[m*8+p], y[m*8+p], acc[p]);
    float s0=acc[0]+acc[4], s1=acc[1]+acc[5], s2=acc[2]+acc[6], s3=acc[3]+acc[7];
    return (s0+s1)+(s2+s3);
}

// ---------- kernels ----------

__global__ void k_fill(float* __restrict__ p, int n, float v){
    int i = blockIdx.x*blockDim.x + threadIdx.x;
    if (i < n) p[i] = v;
}

__global__ __launch_bounds__(128) void k_pifsums(const float* __restrict__ pif,
        float* __restrict__ rvec, float* __restrict__ cvec, float* __restrict__ scal){
    int t = threadIdx.x;
    float rs = np_leaf128(pif + t*DFEAT);
    rvec[t] = rs;
    float cs = pif[t];
    for (int i=1;i<DFEAT;i++) cs += pif[i*DFEAT + t];
    cvec[t] = cs;
    __shared__ float ld[128];
    ld[t] = rs; __syncthreads();
    for (int h=64; h>=1; h>>=1){
        if (t<h) ld[t] = ld[2*t] + ld[2*t+1];
        __syncthreads();
    }
    if (t==0) scal[0] = ld[0];
}

// t1[i] = (X*X)[i,:] @ r — sgemv_t: 8 lanes stride-8 + blas hsum
__global__ __launch_bounds__(256) void k_tvec(const float* __restrict__ M,
        const float* __restrict__ r, float* __restrict__ out){
    int row = blockIdx.x*32 + (threadIdx.x >> 3);
    int p   = threadIdx.x & 7;
    const float* mr = M + (size_t)row*DFEAT;
    float acc = 0.f;
    #pragma unroll
    for (int m=0;m<16;m++){
        float x = mr[p + 8*m];
        float xx = x*x;
        acc = fmaf(xx, r[p + 8*m], acc);
    }
    acc += __shfl_xor(acc, 4);
    acc += __shfl_xor(acc, 1);
    acc += __shfl_xor(acc, 2);
    if (p==0) out[row] = acc;
}

// W = X @ pi_f : per-output sequential k-chain
__global__ __launch_bounds__(256) void k_gemm_w(const float* __restrict__ X,
        const float* __restrict__ pif, float* __restrict__ W){
    int o = blockIdx.x*256 + threadIdx.x;
    int i = o >> 7, j = o & 127;
    const float* xr = X + (size_t)i*DFEAT;
    float acc = 0.f;
    #pragma unroll 8
    for (int k=0;k<DFEAT;k++) acc = fmaf(xr[k], pif[k*DFEAT + j], acc);
    W[o] = acc;
}

// C = (t1+t2) + (-2 * W@Y^T); per-output sequential k-chain; block min/max
__global__ __launch_bounds__(256) void k_gemm_c(const float* __restrict__ W, const float* __restrict__ Y,
        const float* __restrict__ t1, const float* __restrict__ t2,
        float* __restrict__ C, float* __restrict__ bmin, float* __restrict__ bmax){
    __shared__ float Ws[16][132];
    __shared__ float Ys[16][132];
    int t = threadIdx.x;
    int bi = blockIdx.y, bj = blockIdx.x;
    for (int l=t; l<2048; l+=256){
        int r = l>>7, k = l&127;
        Ws[r][k] = W[(size_t)(bi*16+r)*DFEAT + k];
        Ys[r][k] = Y[(size_t)(bj*16+r)*DFEAT + k];
    }
    __syncthreads();
    int a = t >> 4, b = t & 15;
    float acc = 0.f;
    #pragma unroll 8
    for (int k=0;k<DFEAT;k++) acc = fmaf(Ws[a][k], Ys[b][k], acc);
    int gi = bi*16 + a, gj = bj*16 + b;
    float t12 = t1[gi] + t2[gj];
    float v   = t12 + (-2.0f*acc);   // *2 exact -> contraction-safe
    C[(size_t)gi*NROW + gj] = v;
    __shared__ float rmn[256], rmx[256];
    rmn[t]=v; rmx[t]=v; __syncthreads();
    for (int s=128;s;s>>=1){
        if (t<s){ rmn[t]=fminf(rmn[t],rmn[t+s]); rmx[t]=fmaxf(rmx[t],rmx[t+s]); }
        __syncthreads();
    }
    if (t==0){ int bid = bi*gridDim.x + bj; bmin[bid]=rmn[0]; bmax[bid]=rmx[0]; }
}

__global__ void k_minmax(const float* __restrict__ bmin, const float* __restrict__ bmax,
                         int n, float* __restrict__ scal){
    int t = threadIdx.x; // 256
    float mn=FLT_MAX, mx=-FLT_MAX;
    for (int i=t;i<n;i+=256){ mn=fminf(mn,bmin[i]); mx=fmaxf(mx,bmax[i]); }
    __shared__ float rmn[256], rmx[256];
    rmn[t]=mn; rmx[t]=mx; __syncthreads();
    for (int s=128;s;s>>=1){
        if (t<s){ rmn[t]=fminf(rmn[t],rmn[t+s]); rmx[t]=fmaxf(rmx[t],rmx[t+s]); }
        __syncthreads();
    }
    if (t==0){
        float cmin=rmn[0], scale=rmx[0]-rmn[0];
        scal[1]=cmin;
        scal[2]=(scale>1e-8f)? scale : 1.0f;
        scal[3]=(scale>1e-8f)? 1.0f  : 0.0f;
    }
}

// K = exp((-((C-cmin)/safe))/0.01f) — fallback (no transpose)
__global__ void k_exp(float* __restrict__ K, const float* __restrict__ scal){
    float cmin=scal[1], safe=scal[2], flag=scal[3];
    int stride = gridDim.x*blockDim.x;
    for (int i = blockIdx.x*blockDim.x+threadIdx.x; i < NROW*NROW; i += stride){
        if (flag > 0.5f){
            float sub = K[i] - cmin;
            float cn  = sub / safe;
            float arg = (-cn) / EPS32;
            K[i] = (float)exp((double)arg);
        } else {
            K[i] = 1.0f;
        }
    }
}

// fast path: K = exp(...) in place AND K^T written to KT (LDS-tiled transpose)
__global__ __launch_bounds__(256) void k_exp_t(float* __restrict__ K, float* __restrict__ KT,
        const float* __restrict__ scal){
    __shared__ float tile[64][65];
    float cmin=scal[1], safe=scal[2], flag=scal[3];
    int bi = blockIdx.y, bj = blockIdx.x;
    int t = threadIdx.x;
    for (int l=t; l<4096; l+=256){
        int r = l>>6, c = l&63;
        size_t idx = (size_t)(bi*64+r)*NROW + bj*64+c;
        float v = K[idx];
        if (flag > 0.5f){
            float sub = v - cmin;
            float cn  = sub / safe;
            float arg = (-cn) / EPS32;
            v = (float)exp((double)arg);
        } else v = 1.0f;
        K[idx] = v;
        tile[c][r] = v;
    }
    __syncthreads();
    for (int l=t; l<4096; l+=256){
        int r = l>>6, c = l&63;
        KT[(size_t)(bj*64+r)*NROW + bi*64+c] = tile[r][c];
    }
}

// a = (mu/(K@b+1e-16))^gamma ; sgemv_t: 8-lane stride-8, blas hsum; 16 rows/block
// (R8's known-good shape: 256 blocks x 128 threads, direct bv reads)
__global__ __launch_bounds__(128) void k_kb_np(const float* __restrict__ K,
        const float* __restrict__ bv, float* __restrict__ av){
    int row = blockIdx.x*16 + (threadIdx.x >> 3);
    int p   = threadIdx.x & 7;
    const float* Kr = K + (size_t)row*NROW;
    float acc = 0.f;
    #pragma unroll 16
    for (int m=0;m<512;m++) acc = fmaf(Kr[p+8*m], bv[p+8*m], acc);
    acc += __shfl_xor(acc, 4);
    acc += __shfl_xor(acc, 1);
    acc += __shfl_xor(acc, 2);
    if (p==0){
        float den = acc + TINY;
        float q   = MU_S / den;
        av[row] = (float)pow((double)q, (double)GAMMA32);
    }
}

// fallback kta (column walk over K)
__global__ __launch_bounds__(256) void k_kta_np(const float* __restrict__ K,
        const float* __restrict__ av, float* __restrict__ kta, float* __restrict__ bv){
    int j = blockIdx.x*256 + threadIdx.x;
    float s = 0.f;
    #pragma unroll 4
    for (int i=0;i<NROW;i++) s = fmaf(av[i], K[(size_t)i*NROW + j], s);
    kta[j] = s;
    bv[j]  = MU_S/(s + TINY);
}

// stage helper: copy chunk c (512 i-values) of 16 KT rows + av into LDS, coalesced
__device__ __forceinline__ void kta_stage(const float* __restrict__ KT,
        const float* __restrict__ av, int j0, int c,
        float (*buf)[516], float* avs, int lane, int nlanes){
    int i0q = c*128;   // float4 base index within a row
    const float4* KT4 = reinterpret_cast<const float4*>(KT);
    for (int l = lane; l < 2048; l += nlanes){
        int col = l >> 7, q = l & 127;
        float4 v = KT4[(size_t)(j0+col)*1024 + i0q + q];
        *reinterpret_cast<float4*>(&buf[col][q*4]) = v;
    }
    const float4* av4 = reinterpret_cast<const float4*>(av);
    float4* avs4 = reinterpret_cast<float4*>(avs);
    for (int l = lane; l < 128; l += nlanes) avs4[l] = av4[i0q + l];
}

// fast kta: producer/consumer. 256 blocks x 256 threads; block owns 16 columns.
// Lanes 0-15 run numpy's EXACT serial 4096-FMA chain (i ascending, single acc)
// reading b128 from LDS; threads 16-255 stage the next 512-i chunk (dbuf).
__global__ __launch_bounds__(256) void k_kta_pc(const float* __restrict__ KT,
        const float* __restrict__ av, float* __restrict__ kta, float* __restrict__ bv){
    __shared__ float buf[2][16][516];   // pad 516: consumer b128 2-way max
    __shared__ float avs[2][512];
    int t = threadIdx.x;
    int j0 = blockIdx.x*16;
    kta_stage(KT, av, j0, 0, buf[0], avs[0], t, 256);
    __syncthreads();
    float s = 0.f;
    for (int c=0; c<8; c++){
        int cur = c & 1;
        if (t >= 16){
            if (c < 7) kta_stage(KT, av, j0, c+1, buf[cur^1], avs[cur^1], t-16, 240);
        } else {
            const float* bc = &buf[cur][t][0];
            const float* ac = &avs[cur][0];
            #pragma unroll 16
            for (int q=0; q<128; q++){
                float4 kv = *reinterpret_cast<const float4*>(&bc[q*4]);
                float4 a4 = *reinterpret_cast<const float4*>(&ac[q*4]);
                s = fmaf(a4.x, kv.x, s);
                s = fmaf(a4.y, kv.y, s);
                s = fmaf(a4.z, kv.z, s);
                s = fmaf(a4.w, kv.w, s);
            }
        }
        __syncthreads();
    }
    if (t < 16){
        int j = j0 + t;
        kta[j] = s;
        bv[j]  = MU_S/(s + TINY);
    }
}

// leaf sums of pi_s_new = (a*K)*b — np two-step rounding
__global__ __launch_bounds__(64) void k_leafs_pisnew(const float* __restrict__ K,
        const float* __restrict__ av, const float* __restrict__ bv, float* __restrict__ leafS){
    int lane = threadIdx.x;
    int row  = blockIdx.x*2 + (lane>>5);
    int L    = lane & 31;
    float a  = av[row];
    const float* Kr = K + (size_t)row*NROW + L*128;
    const float* br = bv + L*128;
    float r0,r1,r2,r3,r4,r5,r6,r7;
    r0=sepf((a*Kr[0])*br[0]); r1=sepf((a*Kr[1])*br[1]);
    r2=sepf((a*Kr[2])*br[2]); r3=sepf((a*Kr[3])*br[3]);
    r4=sepf((a*Kr[4])*br[4]); r5=sepf((a*Kr[5])*br[5]);
    r6=sepf((a*Kr[6])*br[6]); r7=sepf((a*Kr[7])*br[7]);
    #pragma unroll
    for (int i=8;i<128;i+=8){
        r0+=sepf((a*Kr[i+0])*br[i+0]); r1+=sepf((a*Kr[i+1])*br[i+1]);
        r2+=sepf((a*Kr[i+2])*br[i+2]); r3+=sepf((a*Kr[i+3])*br[i+3]);
        r4+=sepf((a*Kr[i+4])*br[i+4]); r5+=sepf((a*Kr[i+5])*br[i+5]);
        r6+=sepf((a*Kr[i+6])*br[i+6]); r7+=sepf((a*Kr[i+7])*br[i+7]);
    }
    leafS[row*32 + L] = ((r0+r1)+(r2+r3)) + ((r4+r5)+(r6+r7));
}

__global__ __launch_bounds__(128) void k_tree1(const float* __restrict__ leafS,
        float* __restrict__ part){
    __shared__ float ld[256];
    int t = threadIdx.x, g = blockIdx.x;
    ld[t]     = leafS[g*256 + t];
    ld[t+128] = leafS[g*256 + t + 128];
    __syncthreads();
    for (int h=128; h>=1; h>>=1){
        if (t<h) ld[t] = ld[2*t] + ld[2*t+1];
        __syncthreads();
    }
    if (t==0) part[g] = ld[0];
}

template<int MODE>
__global__ __launch_bounds__(256) void k_tree2(const float* __restrict__ part,
        float* __restrict__ scal){
    __shared__ float ld[512];
    int t = threadIdx.x;
    ld[t]     = part[t];
    ld[t+256] = part[t+256];
    __syncthreads();
    for (int h=256; h>=1; h>>=1){
        if (t<h) ld[t] = ld[2*t] + ld[2*t+1];
        __syncthreads();
    }
    if (t==0){
        float S = ld[0];
        if (MODE==0) scal[4] = scal[0]/(S + TINY);
        else         scal[5] = S;
    }
}

// in place: K -> pi_s = ((a*K)*b)*ratio  (final mul feeds a STORE -> safe)
__global__ void k_finalize(float* __restrict__ K, const float* __restrict__ av,
        const float* __restrict__ bv, const float* __restrict__ scal){
    float ratio = scal[4];
    int stride = gridDim.x*blockDim.x;
    for (int idx = blockIdx.x*blockDim.x+threadIdx.x; idx < NROW*NROW; idx += stride){
        int row = idx >> 12, col = idx & 4095;
        K[idx] = ((av[row]*K[idx])*bv[col])*ratio;
    }
}

// row sums of pi_s (np pairwise: 32 leaves + balanced xor tree) + leafS for total
__global__ __launch_bounds__(64) void k_rows_np(const float* __restrict__ P,
        float* __restrict__ rsf, float* __restrict__ leafS){
    int lane = threadIdx.x;
    int row  = blockIdx.x*2 + (lane>>5);
    int L    = lane & 31;
    float leaf = np_leaf128(P + (size_t)row*NROW + L*128);
    leafS[row*32 + L] = leaf;
    float s = leaf;
    s += __shfl_xor(s, 1);
    s += __shfl_xor(s, 2);
    s += __shfl_xor(s, 4);
    s += __shfl_xor(s, 8);
    s += __shfl_xor(s, 16);
    if (L==0) rsf[row] = s;
}

// fallback col sums of pi_s
__global__ __launch_bounds__(256) void k_cols_np(const float* __restrict__ P,
        float* __restrict__ csf){
    int j = blockIdx.x*256 + threadIdx.x;
    float s = P[j];
    #pragma unroll 4
    for (int i=1;i<NROW;i++) s += P[(size_t)i*NROW + j];
    csf[j] = s;
}

// fast col sums: recompute pi_s from K^T (bit-identical mul chain).
// sepf() REQUIRED: blocks fusing *ratio into the add (R8 drift).
__global__ __launch_bounds__(64) void k_cols_fast(const float* __restrict__ KT,
        const float* __restrict__ av, const float* __restrict__ bv,
        const float* __restrict__ scal, float* __restrict__ csf){
    int j = blockIdx.x*64 + threadIdx.x;
    float b = bv[j], ratio = scal[4];
    const float4* row = reinterpret_cast<const float4*>(KT + (size_t)j*NROW);
    float s = 0.f;
    #pragma unroll 8
    for (int i4=0; i4<1024; i4++){
        float4 kv = row[i4];
        s += sepf(((av[i4*4+0]*kv.x)*b)*ratio);
        s += sepf(((av[i4*4+1]*kv.y)*b)*ratio);
        s += sepf(((av[i4*4+2]*kv.z)*b)*ratio);
        s += sepf(((av[i4*4+3]*kv.w)*b)*ratio);
    }
    csf[j] = s;
}

// t_f[k] = (X*X).T @ r : sgemv_n = sequential over i, single acc per k
__global__ __launch_bounds__(128) void k_tvec_f(const float* __restrict__ M,
        const float* __restrict__ r, float* __restrict__ out){
    int k = threadIdx.x;
    float s = 0.f;
    #pragma unroll 8
    for (int i=0;i<NROW;i++){
        float x = M[(size_t)i*DFEAT + k];
        float xx = x*x;
        s = fmaf(xx, r[i], s);
    }
    out[k] = s;
}

// fallback U = X^T @ pi_s (kc=384 block partials)
__global__ __launch_bounds__(256) void k_U(const float* __restrict__ X,
        const float* __restrict__ P, float* __restrict__ U){
    int o = blockIdx.x*256 + threadIdx.x;
    int j = o & 4095, k = o >> 12;
    float acc = 0.f;
    for (int t=0; t<11; t++){
        int i0 = t*384;
        int len = (i0+384 <= NROW) ? 384 : (NROW - i0);
        float part = 0.f;
        #pragma unroll 4
        for (int q=0;q<len;q++)
            part = fmaf(X[(size_t)(i0+q)*DFEAT + k], P[(size_t)(i0+q)*NROW + j], part);
        acc = (t==0) ? part : acc + part;
    }
    U[(size_t)k*NROW + j] = acc;
}

// fast U: pi_s recomputed from K^T stream ('p' feeds a MUL -> contraction-safe)
__global__ __launch_bounds__(64) void k_U_fast(const float* __restrict__ X,
        const float* __restrict__ KT, const float* __restrict__ av,
        const float* __restrict__ bv, const float* __restrict__ scal,
        float* __restrict__ U){
    int j  = (blockIdx.x >> 3)*64 + threadIdx.x;
    int k0 = (blockIdx.x & 7)*16;
    float b = bv[j], ratio = scal[4];
    const float* ktrow = KT + (size_t)j*NROW;
    float acc[16];
    for (int t=0; t<11; t++){
        int i0 = t*384;
        int len = (i0+384 <= NROW) ? 384 : (NROW - i0);
        float part[16];
        #pragma unroll
        for (int d=0;d<16;d++) part[d]=0.f;
        #pragma unroll 4
        for (int q=0;q<len;q++){
            float kt = ktrow[i0+q];
            float p  = ((av[i0+q]*kt)*b)*ratio;   // == pi_s[i0+q][j] bit-exact
            const float* xr = X + (size_t)(i0+q)*DFEAT + k0;
            #pragma unroll
            for (int d=0;d<16;d++) part[d] = fmaf(xr[d], p, part[d]);
        }
        #pragma unroll
        for (int d=0;d<16;d++) acc[d] = (t==0)? part[d] : acc[d]+part[d];
    }
    #pragma unroll
    for (int d=0;d<16;d++) U[(size_t)(k0+d)*NROW + j] = acc[d];
}

// V = U @ Y ; C_f = (t1f+t2f) + (-2*V)
__global__ __launch_bounds__(256) void k_V(const float* __restrict__ U,
        const float* __restrict__ Y, const float* __restrict__ t1f,
        const float* __restrict__ t2f, float* __restrict__ Cf){
    int o = blockIdx.x*256 + threadIdx.x;   // 16384
    int k = o >> 7, l = o & 127;
    float acc = 0.f;
    for (int t=0; t<11; t++){
        int j0 = t*384;
        int len = (j0+384 <= NROW) ? 384 : (NROW - j0);
        float part = 0.f;
        #pragma unroll 4
        for (int q=0;q<len;q++)
            part = fmaf(U[(size_t)k*NROW + j0+q], Y[(size_t)(j0+q)*DFEAT + l], part);
        acc = (t==0) ? part : acc + part;
    }
    float t12 = t1f[k] + t2f[l];
    Cf[o] = t12 + (-2.0f*acc);   // *2 exact -> safe
}

// feature Sinkhorn, np-kernel-exact, 100 iters; writes pi_f
__global__ __launch_bounds__(128) void k_sinkhorn_f_np(const float* __restrict__ Cf,
        const float* __restrict__ scal, float* __restrict__ pif){
    __shared__ float kf[128][129];
    __shared__ float a_s[128], b_s[128];
    __shared__ float red[128];
    __shared__ float cmin_sh, safe_sh, flag_sh, fsc_sh;
    int t = threadIdx.x;
    for (int idx=t; idx<16384; idx+=128) kf[idx>>7][idx&127] = Cf[idx];
    __syncthreads();
    float mn = kf[t][0], mx = kf[t][0];
    for (int c=1;c<128;c++){ float v=kf[t][c]; mn=fminf(mn,v); mx=fmaxf(mx,v); }
    red[t]=mn; __syncthreads();
    for (int s=64;s;s>>=1){ if(t<s) red[t]=fminf(red[t],red[t+s]); __syncthreads(); }
    if (t==0) cmin_sh = red[0];
    __syncthreads();
    red[t]=mx; __syncthreads();
    for (int s=64;s;s>>=1){ if(t<s) red[t]=fmaxf(red[t],red[t+s]); __syncthreads(); }
    if (t==0){
        float scale = red[0] - cmin_sh;
        safe_sh = (scale>1e-8f)? scale : 1.0f;
        flag_sh = (scale>1e-8f)? 1.0f  : 0.0f;
    }
    __syncthreads();
    float cmin=cmin_sh, safe=safe_sh, flag=flag_sh;
    for (int c=0;c<128;c++){
        if (flag > 0.5f){
            float sub = kf[t][c] - cmin;
            float cn  = sub / safe;
            float arg = (-cn) / EPS32;
            kf[t][c]  = (float)exp((double)arg);
        } else kf[t][c] = 1.0f;
    }
    b_s[t] = 1.0f;
    __syncthreads();
    float x[128];
    #pragma unroll 4
    for (int c=0;c<128;c++) x[c] = kf[t][c];
    for (int it=0; it<100; it++){
        float kb = blas_dot128(x, b_s);
        a_s[t] = MU_F/(kb + TINY);
        __syncthreads();
        float s = 0.f;
        #pragma unroll 4
        for (int i=0;i<128;i++) s = fmaf(a_s[i], kf[i][t], s);
        b_s[t] = MU_F/(s + TINY);
        __syncthreads();
    }
    float ar = a_s[t];
    float e[128];
    #pragma unroll 4
    for (int c=0;c<128;c++) e[c] = sepf((ar*x[c])*b_s[c]);
    {
        float r0=e[0],r1=e[1],r2=e[2],r3=e[3],r4=e[4],r5=e[5],r6=e[6],r7=e[7];
        #pragma unroll
        for (int i=8;i<128;i+=8){
            r0+=e[i+0]; r1+=e[i+1]; r2+=e[i+2]; r3+=e[i+3];
            r4+=e[i+4]; r5+=e[i+5]; r6+=e[i+6]; r7+=e[i+7];
        }
        red[t] = ((r0+r1)+(r2+r3)) + ((r4+r5)+(r6+r7));
    }
    __syncthreads();
    for (int h=64; h>=1; h>>=1){
        if (t<h) red[t] = red[2*t] + red[2*t+1];
        __syncthreads();
    }
    if (t==0) fsc_sh = scal[5]/(red[0] + TINY);
    __syncthreads();
    float fsc = fsc_sh;
    #pragma unroll 4
    for (int c=0;c<128;c++) pif[t*DFEAT + c] = e[c]*fsc;
}

extern "C" void kernel_launch(void* const* d_in, const int* in_sizes, int n_in,
                              void* d_out, int out_size, void* d_ws, size_t ws_size,
                              hipStream_t stream){
    const float* X = (const float*)d_in[0];
    const float* Y = (const float*)d_in[1];
    float* out  = (float*)d_out;
    float* Kmat = out;                        // C -> K -> pi_s in place
    float* pif  = out + (size_t)NROW*NROW;    // pi_f (state + output 1)
    float* w = (float*)d_ws;
    float* W      = w;                        // 524288
    float* U      = W      + 524288;          // 524288
    float* leafS  = U      + 524288;          // 131072
    float* part   = leafS  + 131072;          // 512
    float* av     = part   + 512;
    float* bv     = av     + 4096;
    float* kta    = bv     + 4096;
    float* rsf    = kta    + 4096;
    float* csf    = rsf    + 4096;
    float* t1     = csf    + 4096;
    float* t2     = t1     + 4096;
    float* bmin   = t2     + 4096;            // 65536
    float* bmax   = bmin   + 65536;           // 65536
    float* rvec   = bmax   + 65536;
    float* cvec   = rvec   + 128;
    float* t1f    = cvec   + 128;
    float* t2f    = t1f    + 128;
    float* Cf     = t2f    + 128;             // 16384
    float* scal   = Cf     + 16384;           // 16
    float* KT     = scal   + 16;              // 16777216 (64 MB), fast path only
    size_t need_floats = (size_t)(KT - w) + (size_t)NROW*NROW;
    bool hasKT = ws_size >= need_floats*sizeof(float);

    k_fill<<<64, 256, 0, stream>>>(pif, 16384, 1.0f/16384.0f);   // 2^-14 exact
    for (int outer=0; outer<5; outer++){
        k_pifsums<<<1, 128, 0, stream>>>(pif, rvec, cvec, scal);
        k_tvec<<<128, 256, 0, stream>>>(X, rvec, t1);
        k_tvec<<<128, 256, 0, stream>>>(Y, cvec, t2);
        k_gemm_w<<<2048, 256, 0, stream>>>(X, pif, W);
        k_gemm_c<<<dim3(256,256), 256, 0, stream>>>(W, Y, t1, t2, Kmat, bmin, bmax);
        k_minmax<<<1, 256, 0, stream>>>(bmin, bmax, 65536, scal);
        if (hasKT) k_exp_t<<<dim3(64,64), 256, 0, stream>>>(Kmat, KT, scal);
        else       k_exp<<<2048, 256, 0, stream>>>(Kmat, scal);
        k_fill<<<16, 256, 0, stream>>>(bv, 4096, 1.0f);
        for (int it=0; it<100; it++){
            k_kb_np<<<256, 128, 0, stream>>>(Kmat, bv, av);
            if (hasKT) k_kta_pc<<<256, 256, 0, stream>>>(KT, av, kta, bv);
            else       k_kta_np<<<16, 256, 0, stream>>>(Kmat, av, kta, bv);
        }
        k_leafs_pisnew<<<2048, 64, 0, stream>>>(Kmat, av, bv, leafS);
        k_tree1<<<512, 128, 0, stream>>>(leafS, part);
        k_tree2<0><<<1, 256, 0, stream>>>(part, scal);           // ratio_s
        k_finalize<<<2048, 256, 0, stream>>>(Kmat, av, bv, scal);// K -> pi_s
        k_rows_np<<<2048, 64, 0, stream>>>(Kmat, rsf, leafS);
        k_tree1<<<512, 128, 0, stream>>>(leafS, part);
        k_tree2<1><<<1, 256, 0, stream>>>(part, scal);           // pis_total
        if (hasKT) k_cols_fast<<<64, 64, 0, stream>>>(KT, av, bv, scal, csf);
        else       k_cols_np<<<16, 256, 0, stream>>>(Kmat, csf);
        k_tvec_f<<<1, 128, 0, stream>>>(X, rsf, t1f);
        k_tvec_f<<<1, 128, 0, stream>>>(Y, csf, t2f);
        if (hasKT) k_U_fast<<<512, 64, 0, stream>>>(X, KT, av, bv, scal, U);
        else       k_U<<<2048, 256, 0, stream>>>(X, Kmat, U);
        k_V<<<64, 256, 0, stream>>>(U, Y, t1f, t2f, Cf);
        k_sinkhorn_f_np<<<1, 128, 0, stream>>>(Cf, scal, pif);
    }
}